// Round 1
// baseline (570.723 us; speedup 1.0000x reference)
//
#include <hip/hip_runtime.h>
#include <climits>

// ---------------- problem constants (mirror reference) ----------------
constexpr int kB  = 64;
constexpr int kG0 = 19, kG1 = 38, kG2 = 76;
constexpr int kN0 = 3 * kG0 * kG0;   // 1083
constexpr int kN1 = 3 * kG1 * kG1;   // 4332
constexpr int kN2 = 3 * kG2 * kG2;   // 17328
constexpr int kN  = kN0 + kN1 + kN2; // 22743
constexpr int kM  = 256;             // M_CAND
constexpr int kTopK = 8;
constexpr float kNEG = -1e9f;

__constant__ float c_anchors[3][3][2] = {
    {{116.f, 90.f}, {156.f, 198.f}, {373.f, 326.f}},
    {{30.f, 61.f},  {62.f, 45.f},   {59.f, 119.f}},
    {{10.f, 13.f},  {16.f, 30.f},   {33.f, 23.f}},
};

__device__ __forceinline__ float sigm(float x) { return 1.0f / (1.0f + expf(-x)); }

// order-preserving float->uint key (ascending). NEG maps below every score>=0.
__device__ __forceinline__ unsigned score_to_key(float s) {
  unsigned fb = __float_as_uint(s);
  unsigned m = (fb & 0x80000000u) ? 0xFFFFFFFFu : 0x80000000u;
  return fb ^ m;
}
__device__ __forceinline__ float key_to_score(unsigned k) {
  unsigned fb = (k & 0x80000000u) ? (k ^ 0x80000000u) : ~k;
  return __uint_as_float(fb);
}

// flat candidate index n -> cell pointer + (level, anchor, row i, col j, stride)
__device__ __forceinline__ const float* cell_ptr(
    const float* p0, const float* p1, const float* p2, int b, int n,
    int& lvl, int& a, int& gi, int& gj, float& stride) {
  const float* src; int G, m;
  if (n < kN0)            { src = p0; G = kG0; lvl = 0; m = n;             stride = 32.f; }
  else if (n < kN0 + kN1) { src = p1; G = kG1; lvl = 1; m = n - kN0;       stride = 16.f; }
  else                    { src = p2; G = kG2; lvl = 2; m = n - kN0 - kN1; stride = 8.f; }
  int gg = G * G;
  a = m / gg;
  int r = m - a * gg;
  gi = r / G;
  gj = r - gi * G;
  return src + (size_t)((((b * 3 + a) * G + gi) * G + gj)) * 26;
}

// ---------------- block reduction helpers (wave=64) ----------------
template <int NW>
__device__ __forceinline__ int blockSum(int v) {
  __shared__ int sh[NW];
  #pragma unroll
  for (int off = 32; off >= 1; off >>= 1) v += __shfl_down(v, off);
  int tid = threadIdx.x;
  if ((tid & 63) == 0) sh[tid >> 6] = v;
  __syncthreads();
  if (tid == 0) {
    int r = sh[0];
    #pragma unroll
    for (int q = 1; q < NW; ++q) r += sh[q];
    sh[0] = r;
  }
  __syncthreads();
  int r = sh[0];
  __syncthreads();
  return r;
}

template <int NW>
__device__ __forceinline__ int blockMin(int v) {
  __shared__ int sh[NW];
  #pragma unroll
  for (int off = 32; off >= 1; off >>= 1) v = min(v, __shfl_down(v, off));
  int tid = threadIdx.x;
  if ((tid & 63) == 0) sh[tid >> 6] = v;
  __syncthreads();
  if (tid == 0) {
    int r = sh[0];
    #pragma unroll
    for (int q = 1; q < NW; ++q) r = min(r, sh[q]);
    sh[0] = r;
  }
  __syncthreads();
  int r = sh[0];
  __syncthreads();
  return r;
}

// max value, ties -> lowest idx (matches argmax / top_k tie rule)
template <int NW>
__device__ __forceinline__ void blockArgmax(float v, int idx, float& rv, int& ri) {
  __shared__ float shv[NW];
  __shared__ int shi[NW];
  float bv = v; int bi = idx;
  #pragma unroll
  for (int off = 32; off >= 1; off >>= 1) {
    float ov = __shfl_down(bv, off);
    int oi = __shfl_down(bi, off);
    if (ov > bv || (ov == bv && oi < bi)) { bv = ov; bi = oi; }
  }
  int tid = threadIdx.x;
  if ((tid & 63) == 0) { shv[tid >> 6] = bv; shi[tid >> 6] = bi; }
  __syncthreads();
  if (tid == 0) {
    float fv = shv[0]; int fi = shi[0];
    #pragma unroll
    for (int q = 1; q < NW; ++q)
      if (shv[q] > fv || (shv[q] == fv && shi[q] < fi)) { fv = shv[q]; fi = shi[q]; }
    shv[0] = fv; shi[0] = fi;
  }
  __syncthreads();
  rv = shv[0]; ri = shi[0];
  __syncthreads();
}

// ---------------- kernel 1: per-cell masked score -> sortable key ----------------
__global__ __launch_bounds__(256) void score_kernel(
    const float* __restrict__ p0, const float* __restrict__ p1, const float* __restrict__ p2,
    unsigned* __restrict__ keys)
{
  int gid = blockIdx.x * 256 + threadIdx.x;
  if (gid >= kB * kN) return;
  int b = gid / kN;
  int n = gid - b * kN;
  int lvl, a, gi, gj; float stride;
  const float* p = cell_ptr(p0, p1, p2, b, n, lvl, a, gi, gj, stride);
  float obj = sigm(p[4]);
  float loc = sigm(p[5]);
  float masked = kNEG;
  if (obj >= 0.6f && loc >= 0.5f) {  // prefilter: softmax only when it can matter
    float t[20];
    #pragma unroll
    for (int c = 0; c < 20; ++c) t[c] = p[6 + c];
    float lm = t[0];
    #pragma unroll
    for (int c = 1; c < 20; ++c) lm = fmaxf(lm, t[c]);
    float se = 0.f;
    #pragma unroll
    for (int c = 0; c < 20; ++c) se += expf(t[c] - lm);
    float cls_conf = 1.0f / se;             // max of softmax == exp(0)/sum
    float conf = obj * cls_conf;
    if (conf >= 0.05f) masked = sqrtf(conf) * sqrtf(loc);  // (obj*cc)^.5 * loc^.5
  }
  keys[gid] = score_to_key(masked);
}

// ---------------- kernel 2: exact top-256 per image via key binary search ----------------
__global__ __launch_bounds__(1024) void select_kernel(
    const unsigned* __restrict__ keys, int* __restrict__ candIdx)
{
  int b = blockIdx.x, tid = threadIdx.x;
  const unsigned* kk = keys + (size_t)b * kN;
  const unsigned keyNEG = score_to_key(kNEG);

  // count valid (score >= 0) entries
  int cv = 0;
  for (int x = tid; x < kN; x += 1024) cv += (kk[x] > keyNEG) ? 1 : 0;
  cv = blockSum<16>(cv);

  unsigned T; int cgt;
  if (cv < kM) {
    T = keyNEG; cgt = cv;  // fewer than 256 valid: rest are NEG filler
  } else {
    // largest t with count(key >= t) >= 256  == key of 256th-largest element
    unsigned lo = keyNEG + 1, hi = 0xFFFFFFFFu;
    while (lo < hi) {
      unsigned d = hi - lo;
      unsigned mid = lo + (d >> 1) + (d & 1u);  // upper mid, overflow-safe
      int cnt = 0;
      for (int x = tid; x < kN; x += 1024) cnt += (kk[x] >= mid) ? 1 : 0;
      cnt = blockSum<16>(cnt);
      if (cnt >= kM) lo = mid; else hi = mid - 1;
    }
    T = lo;
    int cnt = 0;
    for (int x = tid; x < kN; x += 1024) cnt += (kk[x] > T) ? 1 : 0;
    cgt = blockSum<16>(cnt);
  }

  __shared__ int sCnt;
  if (tid == 0) sCnt = 0;
  __syncthreads();
  int* ci = candIdx + (size_t)b * kM;
  for (int x = tid; x < kN; x += 1024) {
    if (kk[x] > T) { int pPos = atomicAdd(&sCnt, 1); ci[pPos] = x; }
  }
  __syncthreads();

  int needed = kM - cgt;  // >= 1 by construction
  if (T == keyNEG) {
    // NEG filler candidates: never kept, never picked, never influence others -> dummies ok
    if (tid >= cgt && tid < kM) ci[tid] = -1;
  } else {
    __shared__ int eqBuf[1024];
    __shared__ int eqCnt;
    if (tid == 0) eqCnt = 0;
    __syncthreads();
    for (int x = tid; x < kN; x += 1024) {
      if (kk[x] == T) { int pPos = atomicAdd(&eqCnt, 1); if (pPos < 1024) eqBuf[pPos] = x; }
    }
    __syncthreads();
    int ce = min(eqCnt, 1024);
    if (ce == needed) {               // common case (typically ce == needed == 1)
      if (tid < needed) ci[cgt + tid] = eqBuf[tid];
    } else {                          // ties at threshold: take smallest original indices
      for (int q = 0; q < needed; ++q) {
        int mv = INT_MAX;
        for (int x = tid; x < ce; x += 1024) mv = min(mv, eqBuf[x]);
        mv = blockMin<16>(mv);
        if (tid == 0) ci[cgt + q] = mv;
        __syncthreads();
        for (int x = tid; x < ce; x += 1024) if (eqBuf[x] == mv) eqBuf[x] = INT_MAX;
        __syncthreads();
      }
    }
  }
}

// ---------------- kernel 3: re-decode 256 candidates, soft-NMS, top-8 output ----------------
__global__ __launch_bounds__(256) void nms_kernel(
    const float* __restrict__ p0, const float* __restrict__ p1, const float* __restrict__ p2,
    const unsigned* __restrict__ keys, const int* __restrict__ candIdx,
    float* __restrict__ out)
{
  int b = blockIdx.x, tid = threadIdx.x;
  __shared__ float cB[kM][4];
  __shared__ int cC[kM];

  int n = candIdx[(size_t)b * kM + tid];
  float x1 = 0.f, y1 = 0.f, x2 = 0.f, y2 = 0.f;
  int myc = 0;
  float s = kNEG;
  if (n >= 0) {
    s = key_to_score(keys[(size_t)b * kN + n]);  // bit-exact score from kernel 1
    int lvl, a, gi, gj; float stride;
    const float* p = cell_ptr(p0, p1, p2, b, n, lvl, a, gi, gj, stride);
    float cx = (sigm(p[0]) + (float)gj) * stride;
    float cy = (sigm(p[1]) + (float)gi) * stride;
    float w = expf(p[2]) * c_anchors[lvl][a][0];  // (exp*anc/stride)*stride == exp*anc exactly
    float h = expf(p[3]) * c_anchors[lvl][a][1];
    x1 = fminf(fmaxf(cx - 0.5f * w, 0.f), 608.f);
    y1 = fminf(fmaxf(cy - 0.5f * h, 0.f), 608.f);
    x2 = fminf(fmaxf(cx + 0.5f * w, 0.f), 608.f);
    y2 = fminf(fmaxf(cy + 0.5f * h, 0.f), 608.f);
    float lm = p[6]; myc = 0;
    #pragma unroll
    for (int c = 1; c < 20; ++c) { float v = p[6 + c]; if (v > lm) { lm = v; myc = c; } }
  }
  cB[tid][0] = x1; cB[tid][1] = y1; cB[tid][2] = x2; cB[tid][3] = y2;
  cC[tid] = myc;
  float myVal = s;   // original (pre-decay) score used for final ranking
  bool kept = false;
  __syncthreads();

  // Gaussian soft-NMS; once max(s) < NMS_T the reference scan is a no-op -> exact early break
  for (int it = 0; it < kM; ++it) {
    float smax; int jm;
    blockArgmax<4>(s, tid, smax, jm);
    if (smax < 0.1f) break;
    float jx1 = cB[jm][0], jy1 = cB[jm][1], jx2 = cB[jm][2], jy2 = cB[jm][3];
    int cj = cC[jm];
    if (myc == cj) {
      float ix1 = fmaxf(jx1, x1), iy1 = fmaxf(jy1, y1);
      float ix2 = fminf(jx2, x2), iy2 = fminf(jy2, y2);
      float inter = fmaxf(ix2 - ix1 + 1.0f, 0.0f) * fmaxf(iy2 - iy1 + 1.0f, 0.0f);
      float a1 = (jx2 - jx1 + 1.0f) * (jy2 - jy1 + 1.0f);
      float a2 = (x2 - x1 + 1.0f) * (y2 - y1 + 1.0f);
      float iou = inter / (a1 + a2 - inter + 1e-16f);
      s *= expf(-(iou * iou) / 0.5f);
    }
    if (tid == jm) { kept = true; s = kNEG; }
    // no extra barrier needed: cross-thread state (cB/cC) is read-only, s is thread-private,
    // and blockArgmax carries the required __syncthreads
  }

  // keep_top_k by ORIGINAL score among kept
  float f = kept ? myVal : kNEG;
  for (int q = 0; q < kTopK; ++q) {
    float fv; int fj;
    blockArgmax<4>(f, tid, fv, fj);
    if (tid == fj) {
      float* o = out + (size_t)(b * kTopK + q) * 6;
      if (fv > kNEG * 0.5f) {
        o[0] = x1; o[1] = y1; o[2] = x2; o[3] = y2; o[4] = myVal; o[5] = (float)myc;
      } else {
        o[0] = 0.f; o[1] = 0.f; o[2] = 0.f; o[3] = 0.f; o[4] = 0.f; o[5] = 0.f;
      }
      f = kNEG;
    }
  }
}

// ---------------- host launch ----------------
extern "C" void kernel_launch(void* const* d_in, const int* in_sizes, int n_in,
                              void* d_out, int out_size, void* d_ws, size_t ws_size,
                              hipStream_t stream) {
  const float* p0 = (const float*)d_in[0];
  const float* p1 = (const float*)d_in[1];
  const float* p2 = (const float*)d_in[2];
  float* out = (float*)d_out;

  // workspace: keys (B*N u32, 5.82 MB) + candIdx (B*256 int, 64 KB)
  unsigned* keys = (unsigned*)d_ws;
  int* candIdx = (int*)(keys + (size_t)kB * kN);

  int total = kB * kN;
  score_kernel<<<(total + 255) / 256, 256, 0, stream>>>(p0, p1, p2, keys);
  select_kernel<<<kB, 1024, 0, stream>>>(keys, candIdx);
  nms_kernel<<<kB, 256, 0, stream>>>(p0, p1, p2, keys, candIdx, out);
}

// Round 2
// 435.118 us; speedup vs baseline: 1.3116x; 1.3116x over previous
//
#include <hip/hip_runtime.h>
#include <climits>

// ---------------- problem constants (mirror reference) ----------------
constexpr int kB  = 64;
constexpr int kG0 = 19, kG1 = 38, kG2 = 76;
constexpr int kN0 = 3 * kG0 * kG0;   // 1083
constexpr int kN1 = 3 * kG1 * kG1;   // 4332
constexpr int kN2 = 3 * kG2 * kG2;   // 17328
constexpr int kN  = kN0 + kN1 + kN2; // 22743
constexpr int kM  = 256;             // M_CAND
constexpr int kTopK = 8;
constexpr float kNEG = -1e9f;

__constant__ float c_anchors[3][3][2] = {
    {{116.f, 90.f}, {156.f, 198.f}, {373.f, 326.f}},
    {{30.f, 61.f},  {62.f, 45.f},   {59.f, 119.f}},
    {{10.f, 13.f},  {16.f, 30.f},   {33.f, 23.f}},
};

__device__ __forceinline__ float sigm(float x) { return 1.0f / (1.0f + expf(-x)); }

// order-preserving float->uint key (ascending). NEG maps below every score>=0.
__device__ __forceinline__ unsigned score_to_key(float s) {
  unsigned fb = __float_as_uint(s);
  unsigned m = (fb & 0x80000000u) ? 0xFFFFFFFFu : 0x80000000u;
  return fb ^ m;
}
__device__ __forceinline__ float key_to_score(unsigned k) {
  unsigned fb = (k & 0x80000000u) ? (k ^ 0x80000000u) : ~k;
  return __uint_as_float(fb);
}

// flat candidate index n -> cell pointer + (level, anchor, row i, col j, stride)
__device__ __forceinline__ const float* cell_ptr(
    const float* p0, const float* p1, const float* p2, int b, int n,
    int& lvl, int& a, int& gi, int& gj, float& stride) {
  const float* src; int G, m;
  if (n < kN0)            { src = p0; G = kG0; lvl = 0; m = n;             stride = 32.f; }
  else if (n < kN0 + kN1) { src = p1; G = kG1; lvl = 1; m = n - kN0;       stride = 16.f; }
  else                    { src = p2; G = kG2; lvl = 2; m = n - kN0 - kN1; stride = 8.f; }
  int gg = G * G;
  a = m / gg;
  int r = m - a * gg;
  gi = r / G;
  gj = r - gi * G;
  return src + (size_t)((((b * 3 + a) * G + gi) * G + gj)) * 26;
}

// ---------------- wave (64-lane) helpers, no LDS, no barriers ----------------
__device__ __forceinline__ void waveArgmax(float& v, int& i) {
  #pragma unroll
  for (int off = 1; off < 64; off <<= 1) {
    float ov = __shfl_xor(v, off);
    int oi = __shfl_xor(i, off);
    if (ov > v || (ov == v && oi < i)) { v = ov; i = oi; }
  }
}
__device__ __forceinline__ float waveMax(float v) {
  #pragma unroll
  for (int off = 1; off < 64; off <<= 1) v = fmaxf(v, __shfl_xor(v, off));
  return v;
}
__device__ __forceinline__ float sel4f(const float a[4], int q) {
  float r = a[0];
  r = (q == 1) ? a[1] : r;
  r = (q == 2) ? a[2] : r;
  r = (q == 3) ? a[3] : r;
  return r;
}
__device__ __forceinline__ int sel4i(const int a[4], int q) {
  int r = a[0];
  r = (q == 1) ? a[1] : r;
  r = (q == 2) ? a[2] : r;
  r = (q == 3) ? a[3] : r;
  return r;
}

// ---------------- kernel 1: per-cell masked score -> sortable key ----------------
__global__ __launch_bounds__(256) void score_kernel(
    const float* __restrict__ p0, const float* __restrict__ p1, const float* __restrict__ p2,
    unsigned* __restrict__ keys)
{
  int gid = blockIdx.x * 256 + threadIdx.x;
  if (gid >= kB * kN) return;
  int b = gid / kN;
  int n = gid - b * kN;
  int lvl, a, gi, gj; float stride;
  const float* p = cell_ptr(p0, p1, p2, b, n, lvl, a, gi, gj, stride);
  float obj = sigm(p[4]);
  float loc = sigm(p[5]);
  float masked = kNEG;
  if (obj >= 0.6f && loc >= 0.5f) {  // prefilter: softmax only when it can matter
    float t[20];
    #pragma unroll
    for (int c = 0; c < 20; ++c) t[c] = p[6 + c];
    float lm = t[0];
    #pragma unroll
    for (int c = 1; c < 20; ++c) lm = fmaxf(lm, t[c]);
    float se = 0.f;
    #pragma unroll
    for (int c = 0; c < 20; ++c) se += expf(t[c] - lm);
    float cls_conf = 1.0f / se;             // max of softmax == exp(0)/sum
    float conf = obj * cls_conf;
    if (conf >= 0.05f) masked = sqrtf(conf) * sqrtf(loc);  // (obj*cc)^.5 * loc^.5
  }
  keys[gid] = score_to_key(masked);
}

// ---------------- kernel 2: exact top-256 per image, 3-pass radix histogram ----------------
// valid keys (score in (0,1]) lie in [0x80000000, 0xBF800000]; invalid are exactly keyNEG.
__global__ __launch_bounds__(512) void select_kernel(
    const unsigned* __restrict__ keys, int* __restrict__ candIdx)
{
  int b = blockIdx.x, tid = threadIdx.x;
  const unsigned* kk = keys + (size_t)b * kN;
  const unsigned keyNEG = score_to_key(kNEG);

  __shared__ int hist[4096];
  __shared__ int eqBuf[1024];
  __shared__ int sB, sCumAbove, sNeeded2, sB2, sPrefix24, sNeeded3;
  __shared__ unsigned sT;
  __shared__ int sCgt;

  // ---- pass 1: top 12 bits (valid keys only; skip NEG to avoid one-bin hammering) ----
  for (int i = tid; i < 4096; i += 512) hist[i] = 0;
  __syncthreads();
  for (int x = tid; x < kN; x += 512) {
    unsigned k = kk[x];
    if (k >= 0x80000000u) atomicAdd(&hist[k >> 20], 1);
  }
  __syncthreads();
  if (tid == 0) {
    int cum = 0, B = -1, cumAbove = 0;
    for (int bin = 0xBF8; bin >= 0x800; --bin) {
      int c = hist[bin];
      if (cum + c >= kM) { B = bin; cumAbove = cum; break; }
      cum += c;
    }
    sB = B; sCumAbove = cumAbove;
    if (B < 0) { sT = keyNEG; sCgt = cum; }       // fewer than 256 valid
    else sNeeded2 = kM - cumAbove;
  }
  __syncthreads();
  int B = sB;

  if (B >= 0) {
    // ---- pass 2: bits 19:8 within bin B ----
    for (int i = tid; i < 4096; i += 512) hist[i] = 0;
    __syncthreads();
    for (int x = tid; x < kN; x += 512) {
      unsigned k = kk[x];
      if ((int)(k >> 20) == B) atomicAdd(&hist[(k >> 8) & 0xFFF], 1);
    }
    __syncthreads();
    if (tid == 0) {
      int cum = 0, B2 = 0, cumAbove2 = 0;
      for (int bin = 4095; bin >= 0; --bin) {
        int c = hist[bin];
        if (cum + c >= sNeeded2) { B2 = bin; cumAbove2 = cum; break; }
        cum += c;
      }
      sB2 = B2;
      sPrefix24 = (B << 12) | B2;
      sNeeded3 = sNeeded2 - cumAbove2;
      sCumAbove += cumAbove2;                     // now count of keys with top24 prefix > (B,B2)
    }
    __syncthreads();
    int prefix24 = sPrefix24;

    // ---- pass 3: low 8 bits within 24-bit prefix ----
    for (int i = tid; i < 256; i += 512) hist[i] = 0;
    __syncthreads();
    for (int x = tid; x < kN; x += 512) {
      unsigned k = kk[x];
      if ((int)(k >> 8) == prefix24) atomicAdd(&hist[k & 0xFF], 1);
    }
    __syncthreads();
    if (tid == 0) {
      int cum = 0, b3 = 0, cumAbove3 = 0;
      for (int bin = 255; bin >= 0; --bin) {
        int c = hist[bin];
        if (cum + c >= sNeeded3) { b3 = bin; cumAbove3 = cum; break; }
        cum += c;
      }
      sT = ((unsigned)prefix24 << 8) | (unsigned)b3;
      sCgt = sCumAbove + cumAbove3;               // exact count of keys > T
    }
    __syncthreads();
  }

  unsigned T = sT;
  int cgt = sCgt;

  // ---- gather: all keys > T, then fill ties (== T) by smallest index ----
  __shared__ int sCnt, eqCnt;
  if (tid == 0) { sCnt = 0; eqCnt = 0; }
  __syncthreads();
  int* ci = candIdx + (size_t)b * kM;
  for (int x = tid; x < kN; x += 512) {
    unsigned k = kk[x];
    if (k > T) { int p = atomicAdd(&sCnt, 1); ci[p] = x; }
    else if (k == T && T != keyNEG) { int p = atomicAdd(&eqCnt, 1); if (p < 1024) eqBuf[p] = x; }
  }
  __syncthreads();

  int needed = kM - cgt;  // >= 1 by construction
  if (T == keyNEG) {
    // NEG filler candidates: never kept, never picked, never influence others -> dummies ok
    if (tid >= cgt && tid < kM) ci[tid] = -1;
  } else {
    int ce = min(eqCnt, 1024);
    if (ce == needed) {               // common case (typically ce == needed == 1)
      if (tid < needed) ci[cgt + tid] = eqBuf[tid];
    } else if (tid == 0) {            // rare tie overflow: take smallest original indices
      for (int q = 0; q < needed; ++q) {
        int mv = INT_MAX, mp = 0;
        for (int x = 0; x < ce; ++x) if (eqBuf[x] < mv) { mv = eqBuf[x]; mp = x; }
        ci[cgt + q] = mv; eqBuf[mp] = INT_MAX;
      }
    }
  }
}

// ---------------- kernel 3: single-wave soft-NMS with exact early stop ----------------
// 64 threads/block, 4 candidates per lane, all state in registers, zero barriers.
__global__ __launch_bounds__(64) void nms_kernel(
    const float* __restrict__ p0, const float* __restrict__ p1, const float* __restrict__ p2,
    const unsigned* __restrict__ keys, const int* __restrict__ candIdx,
    float* __restrict__ out)
{
  int b = blockIdx.x, lane = threadIdx.x;

  float x1[4], y1[4], x2[4], y2[4], val[4], s[4];
  int cls[4];
  bool kept[4];

  #pragma unroll
  for (int q = 0; q < 4; ++q) {
    int n = candIdx[(size_t)b * kM + q * 64 + lane];   // coalesced
    kept[q] = false;
    x1[q] = y1[q] = x2[q] = y2[q] = 0.f;
    cls[q] = 0; val[q] = kNEG; s[q] = kNEG;
    if (n >= 0) {
      float sc = key_to_score(keys[(size_t)b * kN + n]);  // bit-exact score from kernel 1
      val[q] = sc; s[q] = sc;
      int lvl, a, gi, gj; float stride;
      const float* p = cell_ptr(p0, p1, p2, b, n, lvl, a, gi, gj, stride);
      float cx = (sigm(p[0]) + (float)gj) * stride;
      float cy = (sigm(p[1]) + (float)gi) * stride;
      float w = expf(p[2]) * c_anchors[lvl][a][0];  // (exp*anc/stride)*stride == exp*anc exactly
      float h = expf(p[3]) * c_anchors[lvl][a][1];
      x1[q] = fminf(fmaxf(cx - 0.5f * w, 0.f), 608.f);
      y1[q] = fminf(fmaxf(cy - 0.5f * h, 0.f), 608.f);
      x2[q] = fminf(fmaxf(cx + 0.5f * w, 0.f), 608.f);
      y2[q] = fminf(fmaxf(cy + 0.5f * h, 0.f), 608.f);
      float lm = p[6]; int mc = 0;
      #pragma unroll
      for (int c = 1; c < 20; ++c) { float v = p[6 + c]; if (v > lm) { lm = v; mc = c; } }
      cls[q] = mc;
    }
  }

  // top-8 kept ORIGINAL scores, maintained identically (uniformly) on all lanes
  float top8[8];
  #pragma unroll
  for (int i = 0; i < 8; ++i) top8[i] = kNEG;
  int keptCount = 0;

  for (int it = 0; it < kM; ++it) {
    // argmax over 256 candidates: 4 local + 64-lane butterfly
    float bv = s[0]; int bq = 0;
    #pragma unroll
    for (int q = 1; q < 4; ++q) if (s[q] > bv) { bv = s[q]; bq = q; }
    int bi = bq * 64 + lane;
    waveArgmax(bv, bi);
    if (bv < 0.1f) break;   // all remaining reference steps are no-ops -> exact

    int wlane = bi & 63, wq = bi >> 6;
    // broadcast winner's data (only winner lane's selected values matter)
    float jx1 = __shfl(sel4f(x1, wq), wlane);
    float jy1 = __shfl(sel4f(y1, wq), wlane);
    float jx2 = __shfl(sel4f(x2, wq), wlane);
    float jy2 = __shfl(sel4f(y2, wq), wlane);
    float jval = __shfl(sel4f(val, wq), wlane);
    int   cj  = __shfl(sel4i(cls, wq), wlane);

    float a1 = (jx2 - jx1 + 1.0f) * (jy2 - jy1 + 1.0f);
    #pragma unroll
    for (int q = 0; q < 4; ++q) {
      if (cls[q] == cj) {
        float ix1 = fmaxf(jx1, x1[q]), iy1 = fmaxf(jy1, y1[q]);
        float ix2 = fminf(jx2, x2[q]), iy2 = fminf(jy2, y2[q]);
        float inter = fmaxf(ix2 - ix1 + 1.0f, 0.0f) * fmaxf(iy2 - iy1 + 1.0f, 0.0f);
        float a2 = (x2[q] - x1[q] + 1.0f) * (y2[q] - y1[q] + 1.0f);
        float iou = inter / (a1 + a2 - inter + 1e-16f);
        s[q] *= expf(-(iou * iou) / 0.5f);
      }
      if (bi == q * 64 + lane) { kept[q] = true; s[q] = kNEG; }  // winner slot
    }

    // early-stop bookkeeping (uniform scalar work on every lane)
    float v = jval;
    #pragma unroll
    for (int i = 0; i < 8; ++i) { float m = fmaxf(top8[i], v); v = fminf(top8[i], v); top8[i] = m; }
    ++keptCount;
    if (keptCount >= kTopK) {
      float am = kNEG;
      #pragma unroll
      for (int q = 0; q < 4; ++q) if (s[q] >= 0.1f) am = fmaxf(am, val[q]);
      am = waveMax(am);
      // no alive candidate's ORIGINAL score can beat the 8th-best kept original:
      // s is monotone non-increasing, originals fixed, kept flags never revert -> exact stop
      if (am < top8[7]) break;
    }
  }

  // keep_top_k by ORIGINAL score among kept
  float f[4];
  #pragma unroll
  for (int q = 0; q < 4; ++q) f[q] = kept[q] ? val[q] : kNEG;
  for (int k = 0; k < kTopK; ++k) {
    float bv = f[0]; int bq = 0;
    #pragma unroll
    for (int q = 1; q < 4; ++q) if (f[q] > bv) { bv = f[q]; bq = q; }
    int bi = bq * 64 + lane;
    waveArgmax(bv, bi);
    int wlane = bi & 63, wq = bi >> 6;
    if (lane == wlane) {
      float* o = out + (size_t)(b * kTopK + k) * 6;
      if (bv > kNEG * 0.5f) {
        o[0] = sel4f(x1, wq); o[1] = sel4f(y1, wq);
        o[2] = sel4f(x2, wq); o[3] = sel4f(y2, wq);
        o[4] = sel4f(val, wq); o[5] = (float)sel4i(cls, wq);
      } else {
        o[0] = 0.f; o[1] = 0.f; o[2] = 0.f; o[3] = 0.f; o[4] = 0.f; o[5] = 0.f;
      }
    }
    #pragma unroll
    for (int q = 0; q < 4; ++q) if (bi == q * 64 + lane) f[q] = kNEG;
  }
}

// ---------------- host launch ----------------
extern "C" void kernel_launch(void* const* d_in, const int* in_sizes, int n_in,
                              void* d_out, int out_size, void* d_ws, size_t ws_size,
                              hipStream_t stream) {
  const float* p0 = (const float*)d_in[0];
  const float* p1 = (const float*)d_in[1];
  const float* p2 = (const float*)d_in[2];
  float* out = (float*)d_out;

  // workspace: keys (B*N u32, 5.82 MB) + candIdx (B*256 int, 64 KB)
  unsigned* keys = (unsigned*)d_ws;
  int* candIdx = (int*)(keys + (size_t)kB * kN);

  int total = kB * kN;
  score_kernel<<<(total + 255) / 256, 256, 0, stream>>>(p0, p1, p2, keys);
  select_kernel<<<kB, 512, 0, stream>>>(keys, candIdx);
  nms_kernel<<<kB, 64, 0, stream>>>(p0, p1, p2, keys, candIdx, out);
}

// Round 3
// 271.315 us; speedup vs baseline: 2.1035x; 1.6037x over previous
//
#include <hip/hip_runtime.h>
#include <climits>

// ---------------- problem constants (mirror reference) ----------------
constexpr int kB  = 64;
constexpr int kG0 = 19, kG1 = 38, kG2 = 76;
constexpr int kN0 = 3 * kG0 * kG0;   // 1083
constexpr int kN1 = 3 * kG1 * kG1;   // 4332
constexpr int kN2 = 3 * kG2 * kG2;   // 17328
constexpr int kN  = kN0 + kN1 + kN2; // 22743
constexpr int kM  = 256;             // M_CAND
constexpr int kTopK = 8;
constexpr float kNEG = -1e9f;

// per-image tiles of 256 cells per level: ceil(1083/256)=5, ceil(4332/256)=17, ceil(17328/256)=68
constexpr int kT0 = 5, kT1 = 17, kT2 = 68;
constexpr int kTilesPerImg = kT0 + kT1 + kT2;  // 90

__constant__ float c_anchors[3][3][2] = {
    {{116.f, 90.f}, {156.f, 198.f}, {373.f, 326.f}},
    {{30.f, 61.f},  {62.f, 45.f},   {59.f, 119.f}},
    {{10.f, 13.f},  {16.f, 30.f},   {33.f, 23.f}},
};

__device__ __forceinline__ float sigm(float x) { return 1.0f / (1.0f + expf(-x)); }

// order-preserving float->uint key (ascending). NEG maps below every score>=0.
__device__ __forceinline__ unsigned score_to_key(float s) {
  unsigned fb = __float_as_uint(s);
  unsigned m = (fb & 0x80000000u) ? 0xFFFFFFFFu : 0x80000000u;
  return fb ^ m;
}
__device__ __forceinline__ float key_to_score(unsigned k) {
  unsigned fb = (k & 0x80000000u) ? (k ^ 0x80000000u) : ~k;
  return __uint_as_float(fb);
}

// flat candidate index n -> cell pointer + (level, anchor, row i, col j, stride)
__device__ __forceinline__ const float* cell_ptr(
    const float* p0, const float* p1, const float* p2, int b, int n,
    int& lvl, int& a, int& gi, int& gj, float& stride) {
  const float* src; int G, m;
  if (n < kN0)            { src = p0; G = kG0; lvl = 0; m = n;             stride = 32.f; }
  else if (n < kN0 + kN1) { src = p1; G = kG1; lvl = 1; m = n - kN0;       stride = 16.f; }
  else                    { src = p2; G = kG2; lvl = 2; m = n - kN0 - kN1; stride = 8.f; }
  int gg = G * G;
  a = m / gg;
  int r = m - a * gg;
  gi = r / G;
  gj = r - gi * G;
  return src + (size_t)((((b * 3 + a) * G + gi) * G + gj)) * 26;
}

// ---------------- wave (64-lane) helpers ----------------
__device__ __forceinline__ void waveArgmax(float& v, int& i) {
  #pragma unroll
  for (int off = 1; off < 64; off <<= 1) {
    float ov = __shfl_xor(v, off);
    int oi = __shfl_xor(i, off);
    if (ov > v || (ov == v && oi < i)) { v = ov; i = oi; }
  }
}
__device__ __forceinline__ float waveMax(float v) {
  #pragma unroll
  for (int off = 1; off < 64; off <<= 1) v = fmaxf(v, __shfl_xor(v, off));
  return v;
}
__device__ __forceinline__ float sel4f(const float a[4], int q) {
  float r = a[0];
  r = (q == 1) ? a[1] : r;
  r = (q == 2) ? a[2] : r;
  r = (q == 3) ? a[3] : r;
  return r;
}
__device__ __forceinline__ int sel4i(const int a[4], int q) {
  int r = a[0];
  r = (q == 1) ? a[1] : r;
  r = (q == 2) ? a[2] : r;
  r = (q == 3) ? a[3] : r;
  return r;
}

// ---------------- kernel 1: tiled, LDS-staged masked score -> sortable key ----------------
__global__ __launch_bounds__(256) void score_kernel(
    const float* __restrict__ p0, const float* __restrict__ p1, const float* __restrict__ p2,
    unsigned* __restrict__ keys)
{
  __shared__ float2 lds2[256 * 13];   // 26624 B: one 256-cell tile, [cell][13 float2]

  int t = threadIdx.x;
  int blk = blockIdx.x;
  int b = blk / kTilesPerImg;
  int r = blk - b * kTilesPerImg;
  const float* slab; int NL, lvlOff, tile;
  if (r < kT0)             { slab = p0; NL = kN0; lvlOff = 0;          tile = r; }
  else if (r < kT0 + kT1)  { slab = p1; NL = kN1; lvlOff = kN0;        tile = r - kT0; }
  else                     { slab = p2; NL = kN2; lvlOff = kN0 + kN1;  tile = r - kT0 - kT1; }
  int cellBase = tile * 256;
  int nc = min(256, NL - cellBase);

  // coalesced float2 staging (all even-float offsets are 8B-aligned: rows are 104 B)
  const float2* g2 = (const float2*)(slab + ((size_t)b * NL + cellBase) * 26);
  int totF2 = nc * 13;
  for (int i = t; i < totF2; i += 256) lds2[i] = g2[i];
  __syncthreads();

  if (t < nc) {
    const float2* c2 = &lds2[t * 13];     // stride-13 f2 = 26-dword stride: 2-way bank alias (free)
    float2 ol = c2[2];                    // channels 4,5
    float obj = sigm(ol.x);
    float loc = sigm(ol.y);
    float tch[20];
    #pragma unroll
    for (int j = 0; j < 10; ++j) { float2 v = c2[3 + j]; tch[2*j] = v.x; tch[2*j+1] = v.y; }
    float lm = tch[0];
    #pragma unroll
    for (int c = 1; c < 20; ++c) lm = fmaxf(lm, tch[c]);
    float se = 0.f;
    #pragma unroll
    for (int c = 0; c < 20; ++c) se += expf(tch[c] - lm);
    float cls_conf = 1.0f / se;           // max of softmax == exp(0)/sum
    float conf = obj * cls_conf;
    float masked = (obj >= 0.6f && loc >= 0.5f && conf >= 0.05f)
                   ? sqrtf(conf) * sqrtf(loc) : kNEG;  // (obj*cc)^.5 * loc^.5
    keys[(size_t)b * kN + lvlOff + cellBase + t] = score_to_key(masked);
  }
}

// ---------------- parallel threshold-bin finder ----------------
// Largest bin B with suffix_count(B) >= needed; cumAbove = count strictly above B; total = all.
// All 512 threads participate uniformly. shWave[8], shOut[2] are caller-provided LDS.
__device__ __forceinline__ void findThresholdBin(
    const int* hist, int NB, int needed,
    int& outB, int& outCumAbove, int& outTotal,
    int* shWave, int* shOut)
{
  int tid = threadIdx.x, lane = tid & 63, w = tid >> 6;
  if (tid == 0) { shOut[0] = -1; shOut[1] = 0; }
  int ipt = (NB + 511) / 512;
  int base = tid * ipt;
  int csum = 0;
  for (int i = 0; i < ipt; ++i) { int bn = base + i; if (bn < NB) csum += hist[bn]; }
  // inclusive suffix scan within wave (lane l gets sum over lanes >= l)
  int v = csum;
  #pragma unroll
  for (int off = 1; off < 64; off <<= 1) {
    int tv = __shfl_down(v, off);
    if (lane + off < 64) v += tv;
  }
  if (lane == 0) shWave[w] = v;   // wave total
  __syncthreads();
  int above = 0, total = 0;
  #pragma unroll
  for (int q = 0; q < 8; ++q) {
    int wt = shWave[q];
    total += wt;
    if (q > w) above += wt;
  }
  int S = v + above;              // suffix count including own chunk
  // exactly one thread's chunk contains the crossing (if total >= needed)
  if (S >= needed && S - csum < needed) {
    int running = S - csum;       // count strictly above my chunk
    for (int i = ipt - 1; i >= 0; --i) {
      int bn = base + i; if (bn >= NB) continue;
      int c = hist[bn];
      if (running + c >= needed) { shOut[0] = bn; shOut[1] = running; break; }
      running += c;
    }
  }
  __syncthreads();
  outB = shOut[0]; outCumAbove = shOut[1]; outTotal = total;
  __syncthreads();
}

// ---------------- kernel 2: exact top-256 per image, 3-pass radix histogram ----------------
// valid keys (score in (0,1]) lie in [0x80000000, 0xBF800000]; invalid are exactly keyNEG.
__global__ __launch_bounds__(512) void select_kernel(
    const unsigned* __restrict__ keys, int* __restrict__ candIdx)
{
  int b = blockIdx.x, tid = threadIdx.x;
  const unsigned* kk = keys + (size_t)b * kN;
  const unsigned keyNEG = score_to_key(kNEG);

  __shared__ int hist[4096];
  __shared__ int eqBuf[1024];
  __shared__ int shWave[8], shOut[2];
  __shared__ unsigned sT;
  __shared__ int sCgt;

  // ---- pass 1: top 12 bits (valid keys only) ----
  for (int i = tid; i < 4096; i += 512) hist[i] = 0;
  __syncthreads();
  for (int x = tid; x < kN; x += 512) {
    unsigned k = kk[x];
    if (k >= 0x80000000u) atomicAdd(&hist[k >> 20], 1);
  }
  __syncthreads();
  int B, cumAbove1, total1;
  findThresholdBin(hist, 4096, kM, B, cumAbove1, total1, shWave, shOut);

  if (total1 < kM) {
    if (tid == 0) { sT = keyNEG; sCgt = total1; }   // fewer than 256 valid
    __syncthreads();
  } else {
    int needed2 = kM - cumAbove1;
    // ---- pass 2: bits 19:8 within bin B ----
    for (int i = tid; i < 4096; i += 512) hist[i] = 0;
    __syncthreads();
    for (int x = tid; x < kN; x += 512) {
      unsigned k = kk[x];
      if ((int)(k >> 20) == B) atomicAdd(&hist[(k >> 8) & 0xFFF], 1);
    }
    __syncthreads();
    int B2, cumAbove2, total2;
    findThresholdBin(hist, 4096, needed2, B2, cumAbove2, total2, shWave, shOut);
    int prefix24 = (B << 12) | B2;
    int needed3 = needed2 - cumAbove2;

    // ---- pass 3: low 8 bits within 24-bit prefix ----
    for (int i = tid; i < 256; i += 512) hist[i] = 0;
    __syncthreads();
    for (int x = tid; x < kN; x += 512) {
      unsigned k = kk[x];
      if ((int)(k >> 8) == prefix24) atomicAdd(&hist[k & 0xFF], 1);
    }
    __syncthreads();
    int B3, cumAbove3, total3;
    findThresholdBin(hist, 256, needed3, B3, cumAbove3, total3, shWave, shOut);
    if (tid == 0) {
      sT = ((unsigned)prefix24 << 8) | (unsigned)B3;
      sCgt = cumAbove1 + cumAbove2 + cumAbove3;     // exact count of keys > T
    }
    __syncthreads();
  }

  unsigned T = sT;
  int cgt = sCgt;

  // ---- gather: all keys > T, then fill ties (== T) by smallest index ----
  __shared__ int sCnt, eqCnt;
  if (tid == 0) { sCnt = 0; eqCnt = 0; }
  __syncthreads();
  int* ci = candIdx + (size_t)b * kM;
  for (int x = tid; x < kN; x += 512) {
    unsigned k = kk[x];
    if (k > T) { int p = atomicAdd(&sCnt, 1); ci[p] = x; }
    else if (k == T && T != keyNEG) { int p = atomicAdd(&eqCnt, 1); if (p < 1024) eqBuf[p] = x; }
  }
  __syncthreads();

  int needed = kM - cgt;  // >= 1 by construction
  if (T == keyNEG) {
    // NEG filler candidates: never kept, never picked, never influence others -> dummies ok
    if (tid >= cgt && tid < kM) ci[tid] = -1;
  } else {
    int ce = min(eqCnt, 1024);
    if (ce == needed) {               // common case (typically ce == needed == 1)
      if (tid < needed) ci[cgt + tid] = eqBuf[tid];
    } else if (tid == 0) {            // rare tie overflow: take smallest original indices
      for (int q = 0; q < needed; ++q) {
        int mv = INT_MAX, mp = 0;
        for (int x = 0; x < ce; ++x) if (eqBuf[x] < mv) { mv = eqBuf[x]; mp = x; }
        ci[cgt + q] = mv; eqBuf[mp] = INT_MAX;
      }
    }
  }
}

// ---------------- kernel 3: single-wave soft-NMS with exact early stop ----------------
// 64 threads/block, 4 candidates per lane, all state in registers, zero barriers.
__global__ __launch_bounds__(64) void nms_kernel(
    const float* __restrict__ p0, const float* __restrict__ p1, const float* __restrict__ p2,
    const unsigned* __restrict__ keys, const int* __restrict__ candIdx,
    float* __restrict__ out)
{
  int b = blockIdx.x, lane = threadIdx.x;

  float x1[4], y1[4], x2[4], y2[4], val[4], s[4];
  int cls[4];
  bool kept[4];

  #pragma unroll
  for (int q = 0; q < 4; ++q) {
    int n = candIdx[(size_t)b * kM + q * 64 + lane];   // coalesced
    kept[q] = false;
    x1[q] = y1[q] = x2[q] = y2[q] = 0.f;
    cls[q] = 0; val[q] = kNEG; s[q] = kNEG;
    if (n >= 0) {
      float sc = key_to_score(keys[(size_t)b * kN + n]);  // bit-exact score from kernel 1
      val[q] = sc; s[q] = sc;
      int lvl, a, gi, gj; float stride;
      const float* p = cell_ptr(p0, p1, p2, b, n, lvl, a, gi, gj, stride);
      const float2* r2 = (const float2*)p;   // rows are 104 B: even-float offsets 8B-aligned
      float2 c01 = r2[0], c23 = r2[1];
      float cx = (sigm(c01.x) + (float)gj) * stride;
      float cy = (sigm(c01.y) + (float)gi) * stride;
      float w = expf(c23.x) * c_anchors[lvl][a][0];  // (exp*anc/stride)*stride == exp*anc exactly
      float h = expf(c23.y) * c_anchors[lvl][a][1];
      x1[q] = fminf(fmaxf(cx - 0.5f * w, 0.f), 608.f);
      y1[q] = fminf(fmaxf(cy - 0.5f * h, 0.f), 608.f);
      x2[q] = fminf(fmaxf(cx + 0.5f * w, 0.f), 608.f);
      y2[q] = fminf(fmaxf(cy + 0.5f * h, 0.f), 608.f);
      float lm = -3.4e38f; int mc = 0;
      #pragma unroll
      for (int j = 3; j < 13; ++j) {
        float2 v = r2[j];
        int c0 = 2 * (j - 3);
        if (v.x > lm) { lm = v.x; mc = c0; }
        if (v.y > lm) { lm = v.y; mc = c0 + 1; }
      }
      cls[q] = mc;
    }
  }

  // top-8 kept ORIGINAL scores, maintained identically (uniformly) on all lanes
  float top8[8];
  #pragma unroll
  for (int i = 0; i < 8; ++i) top8[i] = kNEG;
  int keptCount = 0;

  for (int it = 0; it < kM; ++it) {
    // argmax over 256 candidates: 4 local + 64-lane butterfly
    float bv = s[0]; int bq = 0;
    #pragma unroll
    for (int q = 1; q < 4; ++q) if (s[q] > bv) { bv = s[q]; bq = q; }
    int bi = bq * 64 + lane;
    waveArgmax(bv, bi);
    if (bv < 0.1f) break;   // all remaining reference steps are no-ops -> exact

    int wlane = bi & 63, wq = bi >> 6;
    // broadcast winner's data (only winner lane's selected values matter)
    float jx1 = __shfl(sel4f(x1, wq), wlane);
    float jy1 = __shfl(sel4f(y1, wq), wlane);
    float jx2 = __shfl(sel4f(x2, wq), wlane);
    float jy2 = __shfl(sel4f(y2, wq), wlane);
    float jval = __shfl(sel4f(val, wq), wlane);
    int   cj  = __shfl(sel4i(cls, wq), wlane);

    float a1 = (jx2 - jx1 + 1.0f) * (jy2 - jy1 + 1.0f);
    #pragma unroll
    for (int q = 0; q < 4; ++q) {
      if (cls[q] == cj) {
        float ix1 = fmaxf(jx1, x1[q]), iy1 = fmaxf(jy1, y1[q]);
        float ix2 = fminf(jx2, x2[q]), iy2 = fminf(jy2, y2[q]);
        float inter = fmaxf(ix2 - ix1 + 1.0f, 0.0f) * fmaxf(iy2 - iy1 + 1.0f, 0.0f);
        float a2 = (x2[q] - x1[q] + 1.0f) * (y2[q] - y1[q] + 1.0f);
        float iou = inter / (a1 + a2 - inter + 1e-16f);
        s[q] *= expf(-(iou * iou) / 0.5f);
      }
      if (bi == q * 64 + lane) { kept[q] = true; s[q] = kNEG; }  // winner slot
    }

    // early-stop bookkeeping (uniform scalar work on every lane)
    float v = jval;
    #pragma unroll
    for (int i = 0; i < 8; ++i) { float m = fmaxf(top8[i], v); v = fminf(top8[i], v); top8[i] = m; }
    ++keptCount;
    if (keptCount >= kTopK) {
      float am = kNEG;
      #pragma unroll
      for (int q = 0; q < 4; ++q) if (s[q] >= 0.1f) am = fmaxf(am, val[q]);
      am = waveMax(am);
      // no alive candidate's ORIGINAL score can beat the 8th-best kept original:
      // s is monotone non-increasing, originals fixed, kept flags never revert -> exact stop
      if (am < top8[7]) break;
    }
  }

  // keep_top_k by ORIGINAL score among kept
  float f[4];
  #pragma unroll
  for (int q = 0; q < 4; ++q) f[q] = kept[q] ? val[q] : kNEG;
  for (int k = 0; k < kTopK; ++k) {
    float bv = f[0]; int bq = 0;
    #pragma unroll
    for (int q = 1; q < 4; ++q) if (f[q] > bv) { bv = f[q]; bq = q; }
    int bi = bq * 64 + lane;
    waveArgmax(bv, bi);
    int wlane = bi & 63, wq = bi >> 6;
    if (lane == wlane) {
      float* o = out + (size_t)(b * kTopK + k) * 6;
      if (bv > kNEG * 0.5f) {
        o[0] = sel4f(x1, wq); o[1] = sel4f(y1, wq);
        o[2] = sel4f(x2, wq); o[3] = sel4f(y2, wq);
        o[4] = sel4f(val, wq); o[5] = (float)sel4i(cls, wq);
      } else {
        o[0] = 0.f; o[1] = 0.f; o[2] = 0.f; o[3] = 0.f; o[4] = 0.f; o[5] = 0.f;
      }
    }
    #pragma unroll
    for (int q = 0; q < 4; ++q) if (bi == q * 64 + lane) f[q] = kNEG;
  }
}

// ---------------- host launch ----------------
extern "C" void kernel_launch(void* const* d_in, const int* in_sizes, int n_in,
                              void* d_out, int out_size, void* d_ws, size_t ws_size,
                              hipStream_t stream) {
  const float* p0 = (const float*)d_in[0];
  const float* p1 = (const float*)d_in[1];
  const float* p2 = (const float*)d_in[2];
  float* out = (float*)d_out;

  // workspace: keys (B*N u32, 5.82 MB) + candIdx (B*256 int, 64 KB)
  unsigned* keys = (unsigned*)d_ws;
  int* candIdx = (int*)(keys + (size_t)kB * kN);

  score_kernel<<<kB * kTilesPerImg, 256, 0, stream>>>(p0, p1, p2, keys);
  select_kernel<<<kB, 512, 0, stream>>>(keys, candIdx);
  nms_kernel<<<kB, 64, 0, stream>>>(p0, p1, p2, keys, candIdx, out);
}